// Round 6
// baseline (202.042 us; speedup 1.0000x reference)
//
#include <hip/hip_runtime.h>

// PatchAttacker: B=32 images 512x512x3, N=6 boxes, patch 512x512x3.
// Final pixel = bilinear(patch) of the LAST valid covering patch box, else image.
// R6: one block per image row (384 thr x 4 floats = 1536 floats = 512 px).
// Row-level box state is block-uniform -> 6 lanes compute it into LDS once.
// Unconditional early float4 NT image load (stream purity + latency hiding),
// per-float 2-op hit test, patch gather only on hit, float4 NT store.

#define Nn 6
#define Pp 512

typedef float v4f __attribute__((ext_vector_type(4)));

__global__ __launch_bounds__(384) void patch_attack_kernel(
    const float* __restrict__ images,  // [B,512,512,3]
    const float* __restrict__ boxes,   // [B,N,4]
    const float* __restrict__ patch,   // [512,512,3]
    float* __restrict__ out)           // [B,512,512,3]
{
    __shared__ int      s_x0[Nn], s_offl[Nn], s_offh[Nn];
    __shared__ unsigned s_w[Nn];            // 0 => row not covered by box n
    __shared__ float    s_sx[Nn], s_wy[Nn], s_omwy[Nn];

    const int row = blockIdx.x;             // 0..16383 (32 imgs x 512 rows)
    const int b   = row >> 9;
    const int y   = row & 511;
    const int tid = threadIdx.x;

    if (tid < Nn) {
        const int n = tid;
        const float* bx = boxes + ((size_t)b * Nn + n) * 4;
        const float ymin = bx[0], xmin = bx[1], ymax = bx[2], xmax = bx[3];
        const float h  = ymax - ymin;
        const float w  = xmax - xmin;
        const float pw = h * 0.5f;          // SCALE
        const float ph = pw;                // ASPECT = 1
        const float oy = ymin + h * 0.5f;
        const float ox = xmin + w * 0.5f;
        float yp = fmaxf(oy - ph * 0.5f, 0.0f);
        float xp = fmaxf(ox - pw * 0.5f, 0.0f);
        yp = (yp + ph > 512.0f) ? (512.0f - ph) : yp;
        xp = (xp + pw > 512.0f) ? (512.0f - pw) : xp;
        const bool valid = ph > 60.0f;      // MIN_PH
        const int hI = (int)ph;             // trunc casts, all >= 0
        const int wI = (int)pw;
        const int y0 = (int)yp;
        const int dy = y - y0;
        const bool rowhit = valid && (unsigned)dy < (unsigned)hI;
        s_w[n]  = rowhit ? (unsigned)wI : 0u;
        s_x0[n] = (int)xp;
        s_sx[n] = 512.0f / (float)(wI > 1 ? wI : 1);
        const float sys = 512.0f / (float)(hI > 1 ? hI : 1);
        float sy = ((float)dy + 0.5f) * sys - 0.5f;
        sy = fminf(fmaxf(sy, 0.0f), 511.0f);
        const int yl = (int)sy;
        const int yh = (yl + 1 < 511) ? (yl + 1) : 511;
        s_wy[n]   = sy - (float)yl;
        s_omwy[n] = 1.0f - s_wy[n];
        s_offl[n] = yl * (Pp * 3);
        s_offh[n] = yh * (Pp * 3);
    }
    __syncthreads();

    const int f0 = tid << 2;                         // float idx in row, 0..1532
    const size_t g = (size_t)row * 1536 + f0;        // 16B aligned
    // early, unconditional, perfectly coalesced stream read
    v4f img = __builtin_nontemporal_load((const v4f*)(images + g));

    // row state -> registers (uniform; single LDS read each)
    unsigned w_[Nn]; int x0_[Nn], offl_[Nn], offh_[Nn];
    float sx_[Nn], wy_[Nn], omwy_[Nn];
    #pragma unroll
    for (int n = 0; n < Nn; ++n) {
        w_[n] = s_w[n];   x0_[n] = s_x0[n];
        offl_[n] = s_offl[n]; offh_[n] = s_offh[n];
        sx_[n] = s_sx[n]; wy_[n] = s_wy[n]; omwy_[n] = s_omwy[n];
    }

    float res[4];
    #pragma unroll
    for (int j = 0; j < 4; ++j) {
        const int f  = f0 + j;
        const int px = f / 3;                        // x coordinate
        const int c  = f - px * 3;                   // channel
        float v = img[j];
        #pragma unroll
        for (int n = Nn - 1; n >= 0; --n) {          // descending = last writer
            const int dx = px - x0_[n];
            if ((unsigned)dx < w_[n]) {
                float sx = ((float)dx + 0.5f) * sx_[n] - 0.5f;
                sx = fminf(fmaxf(sx, 0.0f), 511.0f);
                const int xl = (int)sx;
                const int xh = (xl + 1 < 511) ? (xl + 1) : 511;
                const float wx   = sx - (float)xl;
                const float omwx = 1.0f - wx;
                const float* __restrict__ rl = patch + offl_[n];
                const float* __restrict__ rh = patch + offh_[n];
                const int al = xl * 3 + c, ah = xh * 3 + c;
                // separable bilinear, same op order as reference
                v = (rl[al] * omwy_[n] + rh[al] * wy_[n]) * omwx
                  + (rl[ah] * omwy_[n] + rh[ah] * wy_[n]) * wx;
                break;
            }
        }
        res[j] = v;
    }

    v4f o = {res[0], res[1], res[2], res[3]};
    __builtin_nontemporal_store(o, (v4f*)(out + g));
}

extern "C" void kernel_launch(void* const* d_in, const int* in_sizes, int n_in,
                              void* d_out, int out_size, void* d_ws, size_t ws_size,
                              hipStream_t stream) {
    const float* images = (const float*)d_in[0];
    const float* boxes  = (const float*)d_in[1];
    const float* patch  = (const float*)d_in[2];
    float* out = (float*)d_out;

    const int rows = 32 * 512;                 // one block per image row
    patch_attack_kernel<<<rows, 384, 0, stream>>>(images, boxes, patch, out);
}